// Round 11
// baseline (150.918 us; speedup 1.0000x reference)
//
#include <hip/hip_runtime.h>
#include <hip/hip_bf16.h>

using short8 = __attribute__((ext_vector_type(8))) short;
using f32x4  = __attribute__((ext_vector_type(4))) float;

#define N_TOK   8192
#define DIM     128
#define JS      32                 // j-splits
#define JCH     (N_TOK / JS)       // 256 j per wave
#define NT      (JCH / 16)         // 16 j-tiles per wave
#define ROWS    32                 // i-rows per wave
#define EXP10F  22026.465794806718f
#define SCALE   3.79828262f        // sqrt(10/ln2): dot of scaled vecs = 10*sim/ln2 -> exp2 arg

// ---------------- Kernel A: row-normalize, scale, cast to bf16, pack keys ----------------
__global__ void norm_cast_kernel(const float* __restrict__ feats,
                                 const int* __restrict__ did,
                                 const int* __restrict__ iid,
                                 __hip_bfloat16* __restrict__ xb,
                                 int* __restrict__ keys,
                                 float* __restrict__ scal /* [sm,sa,cnt,counter] */) {
  const int wid  = threadIdx.x >> 6;
  const int lane = threadIdx.x & 63;
  const int row  = blockIdx.x * 4 + wid;   // one wave per row
  if (blockIdx.x == 0 && threadIdx.x < 4) scal[threadIdx.x] = 0.0f;  // zero loss accumulators
  const float2 v = *reinterpret_cast<const float2*>(feats + row * DIM + lane * 2);
  float ss = v.x * v.x + v.y * v.y;
  #pragma unroll
  for (int m = 1; m < 64; m <<= 1) ss += __shfl_xor(ss, m, 64);
  const float scale = SCALE / fmaxf(sqrtf(ss), 1e-12f);
  __hip_bfloat162 pair;
  pair.x = __float2bfloat16(v.x * scale);
  pair.y = __float2bfloat16(v.y * scale);
  *reinterpret_cast<__hip_bfloat162*>(xb + row * DIM + lane * 2) = pair;
  if (lane == 0) keys[row] = (did[row] << 5) | iid[row];   // did in [0,4), iid in [0,32)
}

// ---------------- Kernel B: fused sim -> exp -> masked row sums (atomic-free) ----------------
// Wave owns 32 i-rows x 256 j-cols. No LDS, no barriers, NO ATOMICS: each wave's
// per-row partial goes to its own slot partial[js][row] (written exactly once).
// Epilogue: N = sum (dds?2:1)*e over all j, P = sum_{same key} e; neg = N - P.
// Diagonal dropped in-kernel; exact exp(10) re-added in loss kernel.
__launch_bounds__(256, 4)
__global__ void sim_kernel(const __hip_bfloat16* __restrict__ xb,
                           const int* __restrict__ keys,
                           float* __restrict__ pospart,
                           float* __restrict__ negpart) {
  const int tid  = threadIdx.x;
  const int lane = tid & 63, wid = tid >> 6;
  const int w    = blockIdx.x * 4 + wid;     // 8192 waves
  const int iw   = w >> 5;                   // 256 i-waves (32 rows each)
  const int js   = w & (JS - 1);
  const int l15  = lane & 15, l4 = lane >> 4;
  const int i0   = iw * ROWS;
  const int jbase = js * JCH;

  // A fragments: rows i0 + m*16 + l15, k = ks*32 + l4*8
  short8 a[2][4];
  #pragma unroll
  for (int m = 0; m < 2; ++m)
    #pragma unroll
    for (int ks = 0; ks < 4; ++ks)
      a[m][ks] = *reinterpret_cast<const short8*>(xb + (size_t)(i0 + m * 16 + l15) * DIM + ks * 32 + l4 * 8);

  // Per-lane i-row keys (C/D layout: row = l4*4 + r)
  int ki[8];
  #pragma unroll
  for (int m = 0; m < 2; ++m)
    #pragma unroll
    for (int r = 0; r < 4; ++r)
      ki[m * 4 + r] = keys[i0 + m * 16 + l4 * 4 + r];

  float aN[8], aP[8];
  #pragma unroll
  for (int t = 0; t < 8; ++t) { aN[t] = 0.0f; aP[t] = 0.0f; }

  short8 b0[4], b1[4];
  int kj0, kj1;

  auto loadB = [&](short8 (&b)[4], int& kj, int t) {
    const int jg = jbase + t * 16 + l15;
    kj = keys[jg];
    const __hip_bfloat16* bp = xb + (size_t)jg * DIM + l4 * 8;
    #pragma unroll
    for (int ks = 0; ks < 4; ++ks)
      b[ks] = *reinterpret_cast<const short8*>(bp + ks * 32);
  };

  auto compute = [&](const short8 (&b)[4], int kj, int t) {
    const int j0 = jbase + t * 16;
    const bool hasdiag = ((unsigned)(j0 - i0) < (unsigned)ROWS);  // wave-uniform
    #pragma unroll
    for (int m = 0; m < 2; ++m) {
      f32x4 acc = {0.0f, 0.0f, 0.0f, 0.0f};
      #pragma unroll
      for (int ks = 0; ks < 4; ++ks)
        acc = __builtin_amdgcn_mfma_f32_16x16x32_bf16(a[m][ks], b[ks], acc, 0, 0, 0);
      #pragma unroll
      for (int r = 0; r < 4; ++r) {
        const int idx = m * 4 + r;
        const int x   = ki[idx] ^ kj;          // 0 => same key; >31 => different dataset
        const float e = __builtin_amdgcn_exp2f(acc[r]);   // = exp(10*sim)
        float nw = (x > 31) ? (e + e) : e;
        float pe = (x == 0) ? e : 0.0f;
        if (hasdiag) {
          const int ig = i0 + m * 16 + l4 * 4 + r;
          const int jg = j0 + l15;
          if (ig == jg) { nw = 0.0f; pe = 0.0f; }   // drop diagonal entirely
        }
        aN[idx] += nw;
        aP[idx] += pe;
      }
    }
  };

  loadB(b0, kj0, 0);
  loadB(b1, kj1, 1);
  for (int t = 0; t < NT - 2; t += 2) {
    compute(b0, kj0, t);
    loadB(b0, kj0, t + 2);
    compute(b1, kj1, t + 1);
    loadB(b1, kj1, t + 3);
  }
  compute(b0, kj0, NT - 2);
  compute(b1, kj1, NT - 1);

  // reduce across the 16 lanes (low 4 bits) holding each row; plain store to own slot
  #pragma unroll
  for (int t = 0; t < 8; ++t) {
    float p = aP[t];
    float q = aN[t] - aP[t];
    #pragma unroll
    for (int m = 1; m < 16; m <<= 1) {
      p += __shfl_xor(p, m, 64);
      q += __shfl_xor(q, m, 64);
    }
    if (l15 == 0) {
      const int ig = i0 + (t >> 2) * 16 + l4 * 4 + (t & 3);
      pospart[js * N_TOK + ig] = p;
      negpart[js * N_TOK + ig] = q;
    }
  }
}

// ---------------- Kernel C: reduce partials -> per-row loss -> masked mean ----------------
// 32 blocks x 256 threads; block b handles rows [b*256, b*256+256). Last-done block
// (device-scope counter) finalizes out[0] from the 3 atomic scalars.
__global__ void loss_kernel(const float* __restrict__ pospart,
                            const float* __restrict__ negpart,
                            float* __restrict__ scal,   // [sm, sa, cnt, counter]
                            float* __restrict__ out) {
  const int tid = threadIdx.x;
  const int row = blockIdx.x * 256 + tid;
  float p = 0.0f, q = 0.0f;
  #pragma unroll
  for (int js = 0; js < JS; ++js) {
    p += pospart[js * N_TOK + row];
    q += negpart[js * N_TOK + row];
  }
  q += EXP10F;                                   // diagonal term, exact
  const float loss = -logf(p / (p + q + 1e-8f));
  float sm = (p > 0.0f) ? loss : 0.0f;
  float sa = loss;
  float c  = (p > 0.0f) ? 1.0f : 0.0f;
  #pragma unroll
  for (int m = 1; m < 64; m <<= 1) {
    sm += __shfl_xor(sm, m, 64);
    sa += __shfl_xor(sa, m, 64);
    c  += __shfl_xor(c, m, 64);
  }
  __shared__ float r[3][4];
  const int lane = tid & 63, wd = tid >> 6;
  if (lane == 0) { r[0][wd] = sm; r[1][wd] = sa; r[2][wd] = c; }
  __syncthreads();
  if (tid == 0) {
    sm = r[0][0] + r[0][1] + r[0][2] + r[0][3];
    sa = r[1][0] + r[1][1] + r[1][2] + r[1][3];
    c  = r[2][0] + r[2][1] + r[2][2] + r[2][3];
    atomicAdd(&scal[0], sm);
    atomicAdd(&scal[1], sa);
    atomicAdd(&scal[2], c);
    __threadfence();
    const unsigned old = atomicAdd(reinterpret_cast<unsigned*>(&scal[3]), 1u);
    if (old == 31u) {    // last block: all scal adds fenced-before their counter adds
      const float tsm = atomicAdd(&scal[0], 0.0f);   // coherent device-scope reads
      const float tsa = atomicAdd(&scal[1], 0.0f);
      const float tc  = atomicAdd(&scal[2], 0.0f);
      out[0] = (tc > 0.5f) ? (tsm / tc) : (tsa / (float)N_TOK);
    }
  }
}

extern "C" void kernel_launch(void* const* d_in, const int* in_sizes, int n_in,
                              void* d_out, int out_size, void* d_ws, size_t ws_size,
                              hipStream_t stream) {
  const float* feats = (const float*)d_in[0];
  const int* did = (const int*)d_in[1];
  const int* iid = (const int*)d_in[2];
  float* out = (float*)d_out;

  char* ws = (char*)d_ws;
  __hip_bfloat16* xb = (__hip_bfloat16*)ws;                        // 2 MB
  int*   keys    = (int*)(ws + (size_t)N_TOK * DIM * 2);           // 32 KB
  float* pospart = (float*)((char*)keys + N_TOK * 4);              // 1 MB
  float* negpart = pospart + JS * N_TOK;                           // 1 MB
  float* scal    = negpart + JS * N_TOK;                           // 16 B

  norm_cast_kernel<<<N_TOK / 4, 256, 0, stream>>>(feats, did, iid, xb, keys, scal);
  sim_kernel<<<(N_TOK / ROWS) * JS / 4, 256, 0, stream>>>(xb, keys, pospart, negpart);
  loss_kernel<<<N_TOK / 256, 256, 0, stream>>>(pospart, negpart, scal, out);
}